// Round 7
// baseline (137.739 us; speedup 1.0000x reference)
//
#include <hip/hip_runtime.h>

// 13-branch fused Conv3d(2->13, k=5, SAME) + bias + clip(0,100)
// K1: X fp32 -> zero-padded bf16 volume P[16][2][68][68][72] in d_ws.
// K2: z-persistent blocks, rolling 8-slot LDS window via global_load_lds,
//     weight-shift MFMA; tile-outer loop so stores overlap next tile's MFMAs.
//     (Round-7 fix: full 4-term shift rotation — a3 carries w4 at sh=3.)
// Fallback (ws too small): round-3 single kernel.

typedef __attribute__((ext_vector_type(8))) short bf16x8;
typedef __attribute__((ext_vector_type(4))) float f32x4;
typedef unsigned short u16;

#define YB 8
#define YR 12
#define ROWB 144              // bytes per padded x-row (72 bf16)
#define SLOTB 2048            // LDS slot stride (1728 used + pad)
#define CIB 16384             // 8 slots per ci
#define ZSTEPS 4              // z-steps per block (2 output planes each)

#define PZ 68
#define PY 68
#define P_PLANE (PY * ROWB)                       // 9792 B
#define P_BYTES ((size_t)16 * 2 * PZ * P_PLANE)   // 21,307,392 B

__device__ __forceinline__ unsigned f2bf(float f) {
    unsigned u = __builtin_bit_cast(unsigned, f);
    return (u + 0x7FFFu + ((u >> 16) & 1u)) >> 16;   // RNE bf16
}

// ---------------- K1: pad + convert ----------------
__global__ __launch_bounds__(256)
void pad_bf16(const float* __restrict__ X, u16* __restrict__ P) {
    int idx = blockIdx.x * 256 + threadIdx.x;    // one per 4 xp elems
    int q = idx % 18;
    int r = idx / 18;
    int yp = r % 68; r /= 68;
    int zp = r % 68; r /= 68;
    int ci = r & 1;
    int b  = r >> 1;
    int z = zp - 2, y = yp - 2;
    bool rowok = ((unsigned)z < 64u) && ((unsigned)y < 64u);
    const float* src = X + ((((size_t)b * 2 + ci) * 64 + z) * 64 + y) * 64;
    u16 h[4];
    #pragma unroll
    for (int j = 0; j < 4; ++j) {
        int x = 4 * q + j - 2;
        float v = (rowok && (unsigned)x < 64u) ? src[x] : 0.0f;
        h[j] = (u16)f2bf(v);
    }
    *(ushort4*)(P + (size_t)idx * 4) = make_ushort4(h[0], h[1], h[2], h[3]);
}

// ---------------- K2: async rolling-window conv ----------------
__device__ __forceinline__ void gl16(const void* g, void* l) {
    __builtin_amdgcn_global_load_lds(
        (const __attribute__((address_space(1))) void*)g,
        (__attribute__((address_space(3))) void*)l, 16, 0, 0);
}

__global__ __launch_bounds__(256, 2)
void conv13_async(const u16* __restrict__ P, const float* __restrict__ W,
                  const float* __restrict__ Bv, float* __restrict__ O) {
    __shared__ char lds[2 * CIB];   // 32768 B

    const int tid = threadIdx.x;
    const int l   = tid & 63;
    const int wid = tid >> 6;
    const int g   = l >> 4;
    const int lx  = l & 15;
    const int yt = blockIdx.x;      // 0..7
    const int zc = blockIdx.y;      // 0..7
    const int b  = blockIdx.z;      // 0..15
    const int zlo = zc * (2 * ZSTEPS);
    const int yp0 = yt * YB;        // padded-y of window start
    const int zz  = wid >> 1;
    const int yy0 = (wid & 1) * 4;

    // ---- A: weight fragments (m=cout=lx, k-row r=4s+g); dz packed in cOffD low bits ----
    unsigned wf[13][3];
    int cOffD[13];
    #pragma unroll
    for (int s = 0; s < 13; ++s) {
        int r  = 4 * s + g;
        int rc = (r < 50) ? r : 49;
        int ci = rc / 25, r2 = rc % 25, dz = r2 / 5, dy = r2 % 5;
        cOffD[s] = (ci * CIB + (yy0 + dy) * ROWB + 8 * lx) | dz;  // base mult of 8
        float w0 = 0.f, w1 = 0.f, w2 = 0.f, w3 = 0.f, w4 = 0.f;
        if (lx < 13 && r < 50) {
            const float* wr = W + ((lx * 2 + ci) * 25 + dz * 5 + dy) * 5;
            w0 = wr[0]; w1 = wr[1]; w2 = wr[2]; w3 = wr[3]; w4 = wr[4];
        }
        wf[s][0] = f2bf(w0) | (f2bf(w1) << 16);
        wf[s][1] = f2bf(w2) | (f2bf(w3) << 16);
        wf[s][2] = f2bf(w4);
    }
    float bvv[4];
    #pragma unroll
    for (int v = 0; v < 4; ++v) {
        int co = 4 * g + v;
        bvv[v] = (co < 13) ? Bv[co] : 0.0f;
    }

    const char* Pc = (const char*)P;
    int c1 = 64 + l; if (c1 > 107) c1 = 107;   // tail-clamped chunk (dups land in pad)

    // ---- initial fill: ci 0..1 x padded planes zlo..zlo+5 -> slots 0..5 ----
    for (int r = wid; r < 12; r += 4) {
        int ci = r / 6, pl = r % 6;
        const char* gb = Pc + (((size_t)(b * 2 + ci) * PZ + (zlo + pl)) * P_PLANE)
                            + (size_t)yp0 * ROWB;
        char* lb = lds + ci * CIB + pl * SLOTB;
        gl16(gb + 16 * l,  lb);
        gl16(gb + 16 * c1, lb + 1024);
    }
    __syncthreads();

    // ---- z-step loop ----
    #pragma unroll 1
    for (int t = 0; t < ZSTEPS; ++t) {
        // A) async DMA for step t+1: planes zlo+2t+6, +7 -> slots (2t+6+pl)&7
        if (t < ZSTEPS - 1) {
            int ci = wid >> 1, pl = wid & 1;
            int slot = (2 * t + 6 + pl) & 7;
            int zp = zlo + 2 * t + 6 + pl;
            const char* gb = Pc + (((size_t)(b * 2 + ci) * PZ + zp) * P_PLANE)
                                + (size_t)yp0 * ROWB;
            char* lb = lds + ci * CIB + slot * SLOTB;
            gl16(gb + 16 * l,  lb);
            gl16(gb + 16 * c1, lb + 1024);
        }

        // B) compute step t, tile-outer: stores of tile i overlap MFMA of tile i+1
        const int uw = 2 * t + zz;
        const int oz = zlo + uw;
        #pragma unroll
        for (int i = 0; i < 4; ++i) {
            f32x4 acc[4];
            #pragma unroll
            for (int sh = 0; sh < 4; ++sh)
                acc[sh] = (f32x4){ bvv[0], bvv[1], bvv[2], bvv[3] };

            #pragma unroll
            for (int s = 0; s < 13; ++s) {
                int cD = cOffD[s];
                int dz = cD & 7;
                int ab = (cD ^ dz) + (((uw + dz) & 7) * SLOTB) + i * ROWB;
                const char* p = lds + ab;
                uint2 lo = *(const uint2*)p;
                uint2 hi = *(const uint2*)(p + 8);
                union { unsigned u[4]; bf16x8 v; } bbv;
                bbv.u[0] = lo.x; bbv.u[1] = lo.y; bbv.u[2] = hi.x; bbv.u[3] = hi.y;

                unsigned a0 = wf[s][0], a1 = wf[s][1], a2 = wf[s][2], a3 = 0u;
                #pragma unroll
                for (int sh = 0; sh < 4; ++sh) {
                    if (sh) {   // full 4-term rotation: a3 carries w4 at sh=3
                        unsigned n1 = (a1 << 16) | (a0 >> 16);
                        unsigned n2 = (a2 << 16) | (a1 >> 16);
                        unsigned n3 = (a3 << 16) | (a2 >> 16);
                        a0 <<= 16; a1 = n1; a2 = n2; a3 = n3;
                    }
                    union { unsigned u[4]; bf16x8 v; } av;
                    av.u[0] = a0; av.u[1] = a1; av.u[2] = a2; av.u[3] = a3;
                    acc[sh] = __builtin_amdgcn_mfma_f32_16x16x32_bf16(av.v, bbv.v, acc[sh], 0, 0, 0);
                }
            }

            // store tile i now (drains in background under tile i+1's MFMAs)
            int oy = yt * YB + yy0 + i;
            float* dst = O + (size_t)b * 3407872 + oz * 4096 + oy * 64 + 4 * lx;
            #pragma unroll
            for (int v = 0; v < 4; ++v) {
                int co = 4 * g + v;
                if (co < 13) {
                    f32x4 o4 = { fminf(fmaxf(acc[0][v], 0.0f), 100.0f),
                                 fminf(fmaxf(acc[1][v], 0.0f), 100.0f),
                                 fminf(fmaxf(acc[2][v], 0.0f), 100.0f),
                                 fminf(fmaxf(acc[3][v], 0.0f), 100.0f) };
                    *(f32x4*)(dst + (size_t)co * 262144) = o4;
                }
            }
        }

        // C) barrier: DMA(t) landed long ago; only last tile's stores are fresh
        __syncthreads();
    }
}

// ---------------- Fallback: round-3 kernel (ws too small) ----------------
#define F_YR 12
#define F_UPITCH 72
#define F_ROWB 144

__global__ __launch_bounds__(256, 2)
void conv13_mfma_shift(const float* __restrict__ X,
                       const float* __restrict__ W,
                       const float* __restrict__ Bv,
                       float* __restrict__ O) {
    __shared__ unsigned short lds[144 * F_UPITCH];

    const int tid = threadIdx.x;
    const int l   = tid & 63;
    const int wid = tid >> 6;
    const int g   = l >> 4;
    const int lx  = l & 15;
    const int yt = blockIdx.x, zt = blockIdx.y, b = blockIdx.z;

    unsigned wf[13][4];
    int rowConst[13];
    #pragma unroll
    for (int s = 0; s < 13; ++s) {
        int r  = 4 * s + g;
        int rc = (r < 50) ? r : 49;
        int ci = rc / 25, r2 = rc % 25, dz = r2 / 5, dy = r2 % 5;
        rowConst[s] = (ci * 72 + dz * F_YR + dy) * F_ROWB;
        float w0 = 0.f, w1 = 0.f, w2 = 0.f, w3 = 0.f, w4 = 0.f;
        if (lx < 13 && r < 50) {
            const float* wr = W + ((lx * 2 + ci) * 25 + dz * 5 + dy) * 5;
            w0 = wr[0]; w1 = wr[1]; w2 = wr[2]; w3 = wr[3]; w4 = wr[4];
        }
        wf[s][0] = f2bf(w0) | (f2bf(w1) << 16);
        wf[s][1] = f2bf(w2) | (f2bf(w3) << 16);
        wf[s][2] = f2bf(w4);
        wf[s][3] = 0u;
    }

    const int gz0 = zt * 2 - 2, gy0 = yt * 8 - 2;
    for (int idx = tid; idx < 144 * 18; idx += 256) {
        int row = idx / 18, q = idx % 18;
        int ci = row / 72;
        int rz = (row / F_YR) % 6;
        int ry = row % F_YR;
        int zi = gz0 + rz, yi = gy0 + ry;
        float v0 = 0.f, v1 = 0.f, v2 = 0.f, v3 = 0.f;
        if ((unsigned)zi < 64u && (unsigned)yi < 64u) {
            const float* src = X + ((((size_t)b * 2 + ci) * 64 + zi) * 64 + yi) * 64;
            int x0 = 4 * q - 2;
            if ((unsigned)(x0 + 0) < 64u) v0 = src[x0 + 0];
            if ((unsigned)(x0 + 1) < 64u) v1 = src[x0 + 1];
            if ((unsigned)(x0 + 2) < 64u) v2 = src[x0 + 2];
            if ((unsigned)(x0 + 3) < 64u) v3 = src[x0 + 3];
        }
        unsigned* lp = (unsigned*)&lds[row * F_UPITCH + 4 * q];
        lp[0] = f2bf(v0) | (f2bf(v1) << 16);
        lp[1] = f2bf(v2) | (f2bf(v3) << 16);
    }

    int tileOff[4], ozv[4], oyv[4];
    #pragma unroll
    for (int i = 0; i < 4; ++i) {
        int t = wid * 4 + i, zz = t >> 3, yy = t & 7;
        tileOff[i] = (zz * F_YR + yy) * F_ROWB;
        ozv[i] = zt * 2 + zz;
        oyv[i] = yt * 8 + yy;
    }
    float bvv[4];
    #pragma unroll
    for (int v = 0; v < 4; ++v) {
        int co = 4 * g + v;
        bvv[v] = (co < 13) ? Bv[co] : 0.0f;
    }
    f32x4 acc[4][4];
    #pragma unroll
    for (int i = 0; i < 4; ++i)
        #pragma unroll
        for (int sh = 0; sh < 4; ++sh)
            acc[i][sh] = (f32x4){ bvv[0], bvv[1], bvv[2], bvv[3] };
    __syncthreads();

    #pragma unroll
    for (int s = 0; s < 13; ++s) {
        bf16x8 bb[4];
        #pragma unroll
        for (int i = 0; i < 4; ++i) {
            const char* p = (const char*)lds + (rowConst[s] + tileOff[i] + 8 * lx);
            uint2 lo = *(const uint2*)p;
            uint2 hi = *(const uint2*)(p + 8);
            union { unsigned u[4]; bf16x8 v; } tmp;
            tmp.u[0] = lo.x; tmp.u[1] = lo.y; tmp.u[2] = hi.x; tmp.u[3] = hi.y;
            bb[i] = tmp.v;
        }
        unsigned a0 = wf[s][0], a1 = wf[s][1], a2 = wf[s][2], a3 = wf[s][3];
        #pragma unroll
        for (int sh = 0; sh < 4; ++sh) {
            if (sh) {
                unsigned n1 = (a1 << 16) | (a0 >> 16);
                unsigned n2 = (a2 << 16) | (a1 >> 16);
                unsigned n3 = (a3 << 16) | (a2 >> 16);
                a0 <<= 16; a1 = n1; a2 = n2; a3 = n3;
            }
            union { unsigned u[4]; bf16x8 v; } av;
            av.u[0] = a0; av.u[1] = a1; av.u[2] = a2; av.u[3] = a3;
            #pragma unroll
            for (int i = 0; i < 4; ++i)
                acc[i][sh] = __builtin_amdgcn_mfma_f32_16x16x32_bf16(av.v, bb[i], acc[i][sh], 0, 0, 0);
        }
    }
    #pragma unroll
    for (int i = 0; i < 4; ++i) {
        float* dst = O + ((((size_t)b * 13) * 64 + ozv[i]) * 64 + oyv[i]) * 64 + 4 * lx;
        #pragma unroll
        for (int v = 0; v < 4; ++v) {
            int co = 4 * g + v;
            if (co < 13) {
                f32x4 o4 = { fminf(fmaxf(acc[i][0][v], 0.0f), 100.0f),
                             fminf(fmaxf(acc[i][1][v], 0.0f), 100.0f),
                             fminf(fmaxf(acc[i][2][v], 0.0f), 100.0f),
                             fminf(fmaxf(acc[i][3][v], 0.0f), 100.0f) };
                *(f32x4*)(dst + (size_t)co * 262144) = o4;
            }
        }
    }
}

extern "C" void kernel_launch(void* const* d_in, const int* in_sizes, int n_in,
                              void* d_out, int out_size, void* d_ws, size_t ws_size,
                              hipStream_t stream) {
    const float* X  = (const float*)d_in[0];
    const float* W  = (const float*)d_in[1];
    const float* Bv = (const float*)d_in[2];
    float* O = (float*)d_out;

    if (ws_size >= P_BYTES) {
        u16* P = (u16*)d_ws;
        pad_bf16<<<10404, 256, 0, stream>>>(X, P);               // 2,663,424 tasks
        conv13_async<<<dim3(8, 8, 16), 256, 0, stream>>>(P, W, Bv, O);
    } else {
        conv13_mfma_shift<<<dim3(8, 32, 16), 256, 0, stream>>>(X, W, Bv, O);
    }
}

// Round 8
// 81.514 us; speedup vs baseline: 1.6898x; 1.6898x over previous
//
#include <hip/hip_runtime.h>

// 13-branch fused Conv3d(2->13, k=5, SAME) + bias + clip(0,100)
// K1: X fp32 -> zero-padded bf16 volume P[16][2][68][68][72] in d_ws.
// K2: z-persistent blocks (ZSTEPS=8, grid 512, 2 blocks/CU), rolling 8-slot
//     LDS window via global_load_lds; weight-shift MFMA; PAIR-split tiles:
//     stores of tile-pair 0 drain under pair 1's MFMAs; shift chain hoisted
//     per (s,pair). launch_bounds(256,1): no VGPR cap -> no spill (r7 lesson).
// Fallback (ws too small): round-3 single kernel.

typedef __attribute__((ext_vector_type(8))) short bf16x8;
typedef __attribute__((ext_vector_type(4))) float f32x4;
typedef unsigned short u16;

#define YB 8
#define YR 12
#define ROWB 144              // bytes per padded x-row (72 bf16)
#define SLOTB 2048            // LDS slot stride (1728 used + pad)
#define CIB 16384             // 8 slots per ci
#define ZSTEPS 8              // z-steps per block (2 output planes each)

#define PZ 68
#define PY 68
#define P_PLANE (PY * ROWB)                       // 9792 B
#define P_BYTES ((size_t)16 * 2 * PZ * P_PLANE)   // 21,307,392 B

__device__ __forceinline__ unsigned f2bf(float f) {
    unsigned u = __builtin_bit_cast(unsigned, f);
    return (u + 0x7FFFu + ((u >> 16) & 1u)) >> 16;   // RNE bf16
}

// ---------------- K1: pad + convert ----------------
__global__ __launch_bounds__(256)
void pad_bf16(const float* __restrict__ X, u16* __restrict__ P) {
    int idx = blockIdx.x * 256 + threadIdx.x;    // one per 4 xp elems
    int q = idx % 18;
    int r = idx / 18;
    int yp = r % 68; r /= 68;
    int zp = r % 68; r /= 68;
    int ci = r & 1;
    int b  = r >> 1;
    int z = zp - 2, y = yp - 2;
    bool rowok = ((unsigned)z < 64u) && ((unsigned)y < 64u);
    const float* src = X + ((((size_t)b * 2 + ci) * 64 + z) * 64 + y) * 64;
    u16 h[4];
    #pragma unroll
    for (int j = 0; j < 4; ++j) {
        int x = 4 * q + j - 2;
        float v = (rowok && (unsigned)x < 64u) ? src[x] : 0.0f;
        h[j] = (u16)f2bf(v);
    }
    *(ushort4*)(P + (size_t)idx * 4) = make_ushort4(h[0], h[1], h[2], h[3]);
}

// ---------------- K2: async rolling-window conv ----------------
__device__ __forceinline__ void gl16(const void* g, void* l) {
    __builtin_amdgcn_global_load_lds(
        (const __attribute__((address_space(1))) void*)g,
        (__attribute__((address_space(3))) void*)l, 16, 0, 0);
}

__global__ __launch_bounds__(256, 1)
void conv13_async(const u16* __restrict__ P, const float* __restrict__ W,
                  const float* __restrict__ Bv, float* __restrict__ O) {
    __shared__ char lds[2 * CIB];   // 32768 B

    const int tid = threadIdx.x;
    const int l   = tid & 63;
    const int wid = tid >> 6;
    const int g   = l >> 4;
    const int lx  = l & 15;
    const int yt = blockIdx.x;      // 0..7
    const int zc = blockIdx.y;      // 0..3
    const int b  = blockIdx.z;      // 0..15
    const int zlo = zc * (2 * ZSTEPS);
    const int yp0 = yt * YB;        // padded-y of window start
    const int zz  = wid >> 1;
    const int yy0 = (wid & 1) * 4;

    // ---- A: weight fragments (m=cout=lx, k-row r=4s+g); dz packed in cOffD low bits ----
    unsigned wf[13][3];
    int cOffD[13];
    #pragma unroll
    for (int s = 0; s < 13; ++s) {
        int r  = 4 * s + g;
        int rc = (r < 50) ? r : 49;
        int ci = rc / 25, r2 = rc % 25, dz = r2 / 5, dy = r2 % 5;
        cOffD[s] = (ci * CIB + (yy0 + dy) * ROWB + 8 * lx) | dz;  // base mult of 8
        float w0 = 0.f, w1 = 0.f, w2 = 0.f, w3 = 0.f, w4 = 0.f;
        if (lx < 13 && r < 50) {
            const float* wr = W + ((lx * 2 + ci) * 25 + dz * 5 + dy) * 5;
            w0 = wr[0]; w1 = wr[1]; w2 = wr[2]; w3 = wr[3]; w4 = wr[4];
        }
        wf[s][0] = f2bf(w0) | (f2bf(w1) << 16);
        wf[s][1] = f2bf(w2) | (f2bf(w3) << 16);
        wf[s][2] = f2bf(w4);
    }
    float bvv[4];
    #pragma unroll
    for (int v = 0; v < 4; ++v) {
        int co = 4 * g + v;
        bvv[v] = (co < 13) ? Bv[co] : 0.0f;
    }

    const char* Pc = (const char*)P;
    int c1 = 64 + l; if (c1 > 107) c1 = 107;   // tail-clamped chunk (dups land in pad)

    // ---- initial fill: ci 0..1 x padded planes zlo..zlo+5 -> slots 0..5 ----
    for (int r = wid; r < 12; r += 4) {
        int ci = r / 6, pl = r % 6;
        const char* gb = Pc + (((size_t)(b * 2 + ci) * PZ + (zlo + pl)) * P_PLANE)
                            + (size_t)yp0 * ROWB;
        char* lb = lds + ci * CIB + pl * SLOTB;
        gl16(gb + 16 * l,  lb);
        gl16(gb + 16 * c1, lb + 1024);
    }
    __syncthreads();

    // ---- z-step loop ----
    #pragma unroll 1
    for (int t = 0; t < ZSTEPS; ++t) {
        // A) async DMA for step t+1: planes zlo+2t+6, +7 -> slots (2t+6+pl)&7
        if (t < ZSTEPS - 1) {
            int ci = wid >> 1, pl = wid & 1;
            int slot = (2 * t + 6 + pl) & 7;
            int zp = zlo + 2 * t + 6 + pl;
            const char* gb = Pc + (((size_t)(b * 2 + ci) * PZ + zp) * P_PLANE)
                                + (size_t)yp0 * ROWB;
            char* lb = lds + ci * CIB + slot * SLOTB;
            gl16(gb + 16 * l,  lb);
            gl16(gb + 16 * c1, lb + 1024);
        }

        // B) compute step t in 2 tile-pairs: pair-0 stores drain under pair-1 MFMAs
        const int uw = 2 * t + zz;
        const int oz = zlo + uw;
        #pragma unroll
        for (int p = 0; p < 2; ++p) {
            f32x4 acc[2][4];
            #pragma unroll
            for (int i = 0; i < 2; ++i)
                #pragma unroll
                for (int sh = 0; sh < 4; ++sh)
                    acc[i][sh] = (f32x4){ bvv[0], bvv[1], bvv[2], bvv[3] };

            #pragma unroll
            for (int s = 0; s < 13; ++s) {
                int cD = cOffD[s];
                int dz = cD & 7;
                int ab = (cD ^ dz) + (((uw + dz) & 7) * SLOTB) + (2 * p) * ROWB;
                union { unsigned u[4]; bf16x8 v; } b0, b1;
                {
                    const char* q0 = lds + ab;
                    uint2 lo = *(const uint2*)q0;
                    uint2 hi = *(const uint2*)(q0 + 8);
                    b0.u[0] = lo.x; b0.u[1] = lo.y; b0.u[2] = hi.x; b0.u[3] = hi.y;
                    const char* q1 = q0 + ROWB;
                    uint2 lo1 = *(const uint2*)q1;
                    uint2 hi1 = *(const uint2*)(q1 + 8);
                    b1.u[0] = lo1.x; b1.u[1] = lo1.y; b1.u[2] = hi1.x; b1.u[3] = hi1.y;
                }
                unsigned a0 = wf[s][0], a1 = wf[s][1], a2 = wf[s][2], a3 = 0u;
                #pragma unroll
                for (int sh = 0; sh < 4; ++sh) {
                    if (sh) {   // full 4-term rotation (a3 carries w4 at sh=3)
                        unsigned n1 = (a1 << 16) | (a0 >> 16);
                        unsigned n2 = (a2 << 16) | (a1 >> 16);
                        unsigned n3 = (a3 << 16) | (a2 >> 16);
                        a0 <<= 16; a1 = n1; a2 = n2; a3 = n3;
                    }
                    union { unsigned u[4]; bf16x8 v; } av;
                    av.u[0] = a0; av.u[1] = a1; av.u[2] = a2; av.u[3] = a3;
                    acc[0][sh] = __builtin_amdgcn_mfma_f32_16x16x32_bf16(av.v, b0.v, acc[0][sh], 0, 0, 0);
                    acc[1][sh] = __builtin_amdgcn_mfma_f32_16x16x32_bf16(av.v, b1.v, acc[1][sh], 0, 0, 0);
                }
            }

            // store pair p (drains under next pair's MFMAs / next step)
            #pragma unroll
            for (int i = 0; i < 2; ++i) {
                int oy = yt * YB + yy0 + 2 * p + i;
                float* dst = O + (size_t)b * 3407872 + oz * 4096 + oy * 64 + 4 * lx;
                #pragma unroll
                for (int v = 0; v < 4; ++v) {
                    int co = 4 * g + v;
                    if (co < 13) {
                        f32x4 o4 = { fminf(fmaxf(acc[i][0][v], 0.0f), 100.0f),
                                     fminf(fmaxf(acc[i][1][v], 0.0f), 100.0f),
                                     fminf(fmaxf(acc[i][2][v], 0.0f), 100.0f),
                                     fminf(fmaxf(acc[i][3][v], 0.0f), 100.0f) };
                        *(f32x4*)(dst + (size_t)co * 262144) = o4;
                    }
                }
            }
        }

        // C) barrier: DMA(t) landed long ago; only pair-1 stores are fresh
        __syncthreads();
    }
}

// ---------------- Fallback: round-3 kernel (ws too small) ----------------
#define F_YR 12
#define F_UPITCH 72
#define F_ROWB 144

__global__ __launch_bounds__(256, 2)
void conv13_mfma_shift(const float* __restrict__ X,
                       const float* __restrict__ W,
                       const float* __restrict__ Bv,
                       float* __restrict__ O) {
    __shared__ unsigned short lds[144 * F_UPITCH];

    const int tid = threadIdx.x;
    const int l   = tid & 63;
    const int wid = tid >> 6;
    const int g   = l >> 4;
    const int lx  = l & 15;
    const int yt = blockIdx.x, zt = blockIdx.y, b = blockIdx.z;

    unsigned wf[13][4];
    int rowConst[13];
    #pragma unroll
    for (int s = 0; s < 13; ++s) {
        int r  = 4 * s + g;
        int rc = (r < 50) ? r : 49;
        int ci = rc / 25, r2 = rc % 25, dz = r2 / 5, dy = r2 % 5;
        rowConst[s] = (ci * 72 + dz * F_YR + dy) * F_ROWB;
        float w0 = 0.f, w1 = 0.f, w2 = 0.f, w3 = 0.f, w4 = 0.f;
        if (lx < 13 && r < 50) {
            const float* wr = W + ((lx * 2 + ci) * 25 + dz * 5 + dy) * 5;
            w0 = wr[0]; w1 = wr[1]; w2 = wr[2]; w3 = wr[3]; w4 = wr[4];
        }
        wf[s][0] = f2bf(w0) | (f2bf(w1) << 16);
        wf[s][1] = f2bf(w2) | (f2bf(w3) << 16);
        wf[s][2] = f2bf(w4);
        wf[s][3] = 0u;
    }

    const int gz0 = zt * 2 - 2, gy0 = yt * 8 - 2;
    for (int idx = tid; idx < 144 * 18; idx += 256) {
        int row = idx / 18, q = idx % 18;
        int ci = row / 72;
        int rz = (row / F_YR) % 6;
        int ry = row % F_YR;
        int zi = gz0 + rz, yi = gy0 + ry;
        float v0 = 0.f, v1 = 0.f, v2 = 0.f, v3 = 0.f;
        if ((unsigned)zi < 64u && (unsigned)yi < 64u) {
            const float* src = X + ((((size_t)b * 2 + ci) * 64 + zi) * 64 + yi) * 64;
            int x0 = 4 * q - 2;
            if ((unsigned)(x0 + 0) < 64u) v0 = src[x0 + 0];
            if ((unsigned)(x0 + 1) < 64u) v1 = src[x0 + 1];
            if ((unsigned)(x0 + 2) < 64u) v2 = src[x0 + 2];
            if ((unsigned)(x0 + 3) < 64u) v3 = src[x0 + 3];
        }
        unsigned* lp = (unsigned*)&lds[row * F_UPITCH + 4 * q];
        lp[0] = f2bf(v0) | (f2bf(v1) << 16);
        lp[1] = f2bf(v2) | (f2bf(v3) << 16);
    }

    int tileOff[4], ozv[4], oyv[4];
    #pragma unroll
    for (int i = 0; i < 4; ++i) {
        int t = wid * 4 + i, zz = t >> 3, yy = t & 7;
        tileOff[i] = (zz * F_YR + yy) * F_ROWB;
        ozv[i] = zt * 2 + zz;
        oyv[i] = yt * 8 + yy;
    }
    float bvv[4];
    #pragma unroll
    for (int v = 0; v < 4; ++v) {
        int co = 4 * g + v;
        bvv[v] = (co < 13) ? Bv[co] : 0.0f;
    }
    f32x4 acc[4][4];
    #pragma unroll
    for (int i = 0; i < 4; ++i)
        #pragma unroll
        for (int sh = 0; sh < 4; ++sh)
            acc[i][sh] = (f32x4){ bvv[0], bvv[1], bvv[2], bvv[3] };
    __syncthreads();

    #pragma unroll
    for (int s = 0; s < 13; ++s) {
        bf16x8 bb[4];
        #pragma unroll
        for (int i = 0; i < 4; ++i) {
            const char* p = (const char*)lds + (rowConst[s] + tileOff[i] + 8 * lx);
            uint2 lo = *(const uint2*)p;
            uint2 hi = *(const uint2*)(p + 8);
            union { unsigned u[4]; bf16x8 v; } tmp;
            tmp.u[0] = lo.x; tmp.u[1] = lo.y; tmp.u[2] = hi.x; tmp.u[3] = hi.y;
            bb[i] = tmp.v;
        }
        unsigned a0 = wf[s][0], a1 = wf[s][1], a2 = wf[s][2], a3 = wf[s][3];
        #pragma unroll
        for (int sh = 0; sh < 4; ++sh) {
            if (sh) {
                unsigned n1 = (a1 << 16) | (a0 >> 16);
                unsigned n2 = (a2 << 16) | (a1 >> 16);
                unsigned n3 = (a3 << 16) | (a2 >> 16);
                a0 <<= 16; a1 = n1; a2 = n2; a3 = n3;
            }
            union { unsigned u[4]; bf16x8 v; } av;
            av.u[0] = a0; av.u[1] = a1; av.u[2] = a2; av.u[3] = a3;
            #pragma unroll
            for (int i = 0; i < 4; ++i)
                acc[i][sh] = __builtin_amdgcn_mfma_f32_16x16x32_bf16(av.v, bb[i], acc[i][sh], 0, 0, 0);
        }
    }
    #pragma unroll
    for (int i = 0; i < 4; ++i) {
        float* dst = O + ((((size_t)b * 13) * 64 + ozv[i]) * 64 + oyv[i]) * 64 + 4 * lx;
        #pragma unroll
        for (int v = 0; v < 4; ++v) {
            int co = 4 * g + v;
            if (co < 13) {
                f32x4 o4 = { fminf(fmaxf(acc[i][0][v], 0.0f), 100.0f),
                             fminf(fmaxf(acc[i][1][v], 0.0f), 100.0f),
                             fminf(fmaxf(acc[i][2][v], 0.0f), 100.0f),
                             fminf(fmaxf(acc[i][3][v], 0.0f), 100.0f) };
                *(f32x4*)(dst + (size_t)co * 262144) = o4;
            }
        }
    }
}

extern "C" void kernel_launch(void* const* d_in, const int* in_sizes, int n_in,
                              void* d_out, int out_size, void* d_ws, size_t ws_size,
                              hipStream_t stream) {
    const float* X  = (const float*)d_in[0];
    const float* W  = (const float*)d_in[1];
    const float* Bv = (const float*)d_in[2];
    float* O = (float*)d_out;

    if (ws_size >= P_BYTES) {
        u16* P = (u16*)d_ws;
        pad_bf16<<<10404, 256, 0, stream>>>(X, P);               // 2,663,424 tasks
        conv13_async<<<dim3(8, 4, 16), 256, 0, stream>>>(P, W, Bv, O);
    } else {
        conv13_mfma_shift<<<dim3(8, 32, 16), 256, 0, stream>>>(X, W, Bv, O);
    }
}

// Round 9
// 77.977 us; speedup vs baseline: 1.7664x; 1.0454x over previous
//
#include <hip/hip_runtime.h>

// 13-branch fused Conv3d(2->13, k=5, SAME) + bias + clip(0,100)
// K1: X fp32 -> zero-padded bf16 volume P[16][2][68][68][72] in d_ws.
// K2: z-persistent blocks (ZSTEPS=8, grid 512), rolling 8-slot LDS window via
//     global_load_lds; weight-shift MFMA (round-5 4-tile loop).
//     Round-9: counted-vmcnt barrier — s_waitcnt vmcnt(16) + raw s_barrier
//     instead of __syncthreads(): waits own 2 DMAs, lets the step's 16 stores
//     drain under next step's MFMAs (kills the 4.3 us/step store-drain stall).
// Fallback (ws too small): round-3 single kernel.

typedef __attribute__((ext_vector_type(8))) short bf16x8;
typedef __attribute__((ext_vector_type(4))) float f32x4;
typedef unsigned short u16;

#define YB 8
#define YR 12
#define ROWB 144              // bytes per padded x-row (72 bf16)
#define SLOTB 2048            // LDS slot stride (1728 used + pad)
#define CIB 16384             // 8 slots per ci
#define ZSTEPS 8              // z-steps per block (2 output planes each)

#define PZ 68
#define PY 68
#define P_PLANE (PY * ROWB)                       // 9792 B
#define P_BYTES ((size_t)16 * 2 * PZ * P_PLANE)   // 21,307,392 B

__device__ __forceinline__ unsigned f2bf(float f) {
    unsigned u = __builtin_bit_cast(unsigned, f);
    return (u + 0x7FFFu + ((u >> 16) & 1u)) >> 16;   // RNE bf16
}

// ---------------- K1: pad + convert ----------------
__global__ __launch_bounds__(256)
void pad_bf16(const float* __restrict__ X, u16* __restrict__ P) {
    int idx = blockIdx.x * 256 + threadIdx.x;    // one per 4 xp elems
    int q = idx % 18;
    int r = idx / 18;
    int yp = r % 68; r /= 68;
    int zp = r % 68; r /= 68;
    int ci = r & 1;
    int b  = r >> 1;
    int z = zp - 2, y = yp - 2;
    bool rowok = ((unsigned)z < 64u) && ((unsigned)y < 64u);
    const float* src = X + ((((size_t)b * 2 + ci) * 64 + z) * 64 + y) * 64;
    u16 h[4];
    #pragma unroll
    for (int j = 0; j < 4; ++j) {
        int x = 4 * q + j - 2;
        float v = (rowok && (unsigned)x < 64u) ? src[x] : 0.0f;
        h[j] = (u16)f2bf(v);
    }
    *(ushort4*)(P + (size_t)idx * 4) = make_ushort4(h[0], h[1], h[2], h[3]);
}

// ---------------- K2: async rolling-window conv ----------------
__device__ __forceinline__ void gl16(const void* g, void* l) {
    __builtin_amdgcn_global_load_lds(
        (const __attribute__((address_space(1))) void*)g,
        (__attribute__((address_space(3))) void*)l, 16, 0, 0);
}

__global__ __launch_bounds__(256, 1)
void conv13_async(const u16* __restrict__ P, const float* __restrict__ W,
                  const float* __restrict__ Bv, float* __restrict__ O) {
    __shared__ char lds[2 * CIB];   // 32768 B

    const int tid = threadIdx.x;
    const int l   = tid & 63;
    const int wid = tid >> 6;
    const int g   = l >> 4;
    const int lx  = l & 15;
    const int yt = blockIdx.x;      // 0..7
    const int zc = blockIdx.y;      // 0..3
    const int b  = blockIdx.z;      // 0..15
    const int zlo = zc * (2 * ZSTEPS);
    const int yp0 = yt * YB;        // padded-y of window start
    const int zz  = wid >> 1;
    const int yy0 = (wid & 1) * 4;

    // ---- A: weight fragments (m=cout=lx, k-row r=4s+g); dz packed in cOffD low bits ----
    unsigned wf[13][3];
    int cOffD[13];
    #pragma unroll
    for (int s = 0; s < 13; ++s) {
        int r  = 4 * s + g;
        int rc = (r < 50) ? r : 49;
        int ci = rc / 25, r2 = rc % 25, dz = r2 / 5, dy = r2 % 5;
        cOffD[s] = (ci * CIB + (yy0 + dy) * ROWB + 8 * lx) | dz;  // base mult of 8
        float w0 = 0.f, w1 = 0.f, w2 = 0.f, w3 = 0.f, w4 = 0.f;
        if (lx < 13 && r < 50) {
            const float* wr = W + ((lx * 2 + ci) * 25 + dz * 5 + dy) * 5;
            w0 = wr[0]; w1 = wr[1]; w2 = wr[2]; w3 = wr[3]; w4 = wr[4];
        }
        wf[s][0] = f2bf(w0) | (f2bf(w1) << 16);
        wf[s][1] = f2bf(w2) | (f2bf(w3) << 16);
        wf[s][2] = f2bf(w4);
    }
    float bvv[4];
    #pragma unroll
    for (int v = 0; v < 4; ++v) {
        int co = 4 * g + v;
        bvv[v] = (co < 13) ? Bv[co] : 0.0f;
    }

    const char* Pc = (const char*)P;
    int c1 = 64 + l; if (c1 > 107) c1 = 107;   // tail-clamped chunk (dups land in pad)

    // ---- initial fill: ci 0..1 x padded planes zlo..zlo+5 -> slots 0..5 ----
    for (int r = wid; r < 12; r += 4) {
        int ci = r / 6, pl = r % 6;
        const char* gb = Pc + (((size_t)(b * 2 + ci) * PZ + (zlo + pl)) * P_PLANE)
                            + (size_t)yp0 * ROWB;
        char* lb = lds + ci * CIB + pl * SLOTB;
        gl16(gb + 16 * l,  lb);
        gl16(gb + 16 * c1, lb + 1024);
    }
    __syncthreads();   // full drain once: initial 6 DMAs visible to all

    // ---- z-step loop ----
    #pragma unroll 1
    for (int t = 0; t < ZSTEPS; ++t) {
        // A) async DMA for step t+1: planes zlo+2t+6, +7 -> slots (2t+6+pl)&7
        //    (disjoint from this step's read slots (2t..2t+5)&7)
        if (t < ZSTEPS - 1) {
            int ci = wid >> 1, pl = wid & 1;
            int slot = (2 * t + 6 + pl) & 7;
            int zp = zlo + 2 * t + 6 + pl;
            const char* gb = Pc + (((size_t)(b * 2 + ci) * PZ + zp) * P_PLANE)
                                + (size_t)yp0 * ROWB;
            char* lb = lds + ci * CIB + slot * SLOTB;
            gl16(gb + 16 * l,  lb);
            gl16(gb + 16 * c1, lb + 1024);
        }

        // B) compute step t: 4 (z,y)-row tiles, shift chain once per s
        const int uw = 2 * t + zz;
        const int oz = zlo + uw;
        f32x4 acc[4][4];
        #pragma unroll
        for (int i = 0; i < 4; ++i)
            #pragma unroll
            for (int sh = 0; sh < 4; ++sh)
                acc[i][sh] = (f32x4){ bvv[0], bvv[1], bvv[2], bvv[3] };

        #pragma unroll
        for (int s = 0; s < 13; ++s) {
            int cD = cOffD[s];
            int dz = cD & 7;
            int ab = (cD ^ dz) + (((uw + dz) & 7) * SLOTB);
            bf16x8 bb[4];
            #pragma unroll
            for (int i = 0; i < 4; ++i) {
                const char* p = lds + ab + i * ROWB;
                uint2 lo = *(const uint2*)p;
                uint2 hi = *(const uint2*)(p + 8);
                union { unsigned u[4]; bf16x8 v; } tmp;
                tmp.u[0] = lo.x; tmp.u[1] = lo.y; tmp.u[2] = hi.x; tmp.u[3] = hi.y;
                bb[i] = tmp.v;
            }
            unsigned a0 = wf[s][0], a1 = wf[s][1], a2 = wf[s][2], a3 = 0u;
            #pragma unroll
            for (int sh = 0; sh < 4; ++sh) {
                if (sh) {   // full 4-term rotation (a3 carries w4 at sh=3)
                    unsigned n1 = (a1 << 16) | (a0 >> 16);
                    unsigned n2 = (a2 << 16) | (a1 >> 16);
                    unsigned n3 = (a3 << 16) | (a2 >> 16);
                    a0 <<= 16; a1 = n1; a2 = n2; a3 = n3;
                }
                union { unsigned u[4]; bf16x8 v; } av;
                av.u[0] = a0; av.u[1] = a1; av.u[2] = a2; av.u[3] = a3;
                #pragma unroll
                for (int i = 0; i < 4; ++i)
                    acc[i][sh] = __builtin_amdgcn_mfma_f32_16x16x32_bf16(av.v, bb[i], acc[i][sh], 0, 0, 0);
            }
        }

        // C) stores: 16 global_store_dwordx4 per wave (drain under next step)
        #pragma unroll
        for (int i = 0; i < 4; ++i) {
            int oy = yt * YB + yy0 + i;
            float* dst = O + (size_t)b * 3407872 + oz * 4096 + oy * 64 + 4 * lx;
            #pragma unroll
            for (int v = 0; v < 4; ++v) {
                int co = 4 * g + v;
                if (co < 13) {
                    f32x4 o4 = { fminf(fmaxf(acc[i][0][v], 0.0f), 100.0f),
                                 fminf(fmaxf(acc[i][1][v], 0.0f), 100.0f),
                                 fminf(fmaxf(acc[i][2][v], 0.0f), 100.0f),
                                 fminf(fmaxf(acc[i][3][v], 0.0f), 100.0f) };
                    *(f32x4*)(dst + (size_t)co * 262144) = o4;
                }
            }
        }

        // D) counted-vmcnt barrier: wait own 2 DMAs (16 newest = this step's
        //    stores stay in flight), then raw barrier. No vmcnt(0) drain.
        asm volatile("s_waitcnt vmcnt(16)" ::: "memory");
        __builtin_amdgcn_s_barrier();
        __builtin_amdgcn_sched_barrier(0);
    }
}

// ---------------- Fallback: round-3 kernel (ws too small) ----------------
#define F_YR 12
#define F_UPITCH 72
#define F_ROWB 144

__global__ __launch_bounds__(256, 2)
void conv13_mfma_shift(const float* __restrict__ X,
                       const float* __restrict__ W,
                       const float* __restrict__ Bv,
                       float* __restrict__ O) {
    __shared__ unsigned short lds[144 * F_UPITCH];

    const int tid = threadIdx.x;
    const int l   = tid & 63;
    const int wid = tid >> 6;
    const int g   = l >> 4;
    const int lx  = l & 15;
    const int yt = blockIdx.x, zt = blockIdx.y, b = blockIdx.z;

    unsigned wf[13][4];
    int rowConst[13];
    #pragma unroll
    for (int s = 0; s < 13; ++s) {
        int r  = 4 * s + g;
        int rc = (r < 50) ? r : 49;
        int ci = rc / 25, r2 = rc % 25, dz = r2 / 5, dy = r2 % 5;
        rowConst[s] = (ci * 72 + dz * F_YR + dy) * F_ROWB;
        float w0 = 0.f, w1 = 0.f, w2 = 0.f, w3 = 0.f, w4 = 0.f;
        if (lx < 13 && r < 50) {
            const float* wr = W + ((lx * 2 + ci) * 25 + dz * 5 + dy) * 5;
            w0 = wr[0]; w1 = wr[1]; w2 = wr[2]; w3 = wr[3]; w4 = wr[4];
        }
        wf[s][0] = f2bf(w0) | (f2bf(w1) << 16);
        wf[s][1] = f2bf(w2) | (f2bf(w3) << 16);
        wf[s][2] = f2bf(w4);
        wf[s][3] = 0u;
    }

    const int gz0 = zt * 2 - 2, gy0 = yt * 8 - 2;
    for (int idx = tid; idx < 144 * 18; idx += 256) {
        int row = idx / 18, q = idx % 18;
        int ci = row / 72;
        int rz = (row / F_YR) % 6;
        int ry = row % F_YR;
        int zi = gz0 + rz, yi = gy0 + ry;
        float v0 = 0.f, v1 = 0.f, v2 = 0.f, v3 = 0.f;
        if ((unsigned)zi < 64u && (unsigned)yi < 64u) {
            const float* src = X + ((((size_t)b * 2 + ci) * 64 + zi) * 64 + yi) * 64;
            int x0 = 4 * q - 2;
            if ((unsigned)(x0 + 0) < 64u) v0 = src[x0 + 0];
            if ((unsigned)(x0 + 1) < 64u) v1 = src[x0 + 1];
            if ((unsigned)(x0 + 2) < 64u) v2 = src[x0 + 2];
            if ((unsigned)(x0 + 3) < 64u) v3 = src[x0 + 3];
        }
        unsigned* lp = (unsigned*)&lds[row * F_UPITCH + 4 * q];
        lp[0] = f2bf(v0) | (f2bf(v1) << 16);
        lp[1] = f2bf(v2) | (f2bf(v3) << 16);
    }

    int tileOff[4], ozv[4], oyv[4];
    #pragma unroll
    for (int i = 0; i < 4; ++i) {
        int t = wid * 4 + i, zz = t >> 3, yy = t & 7;
        tileOff[i] = (zz * F_YR + yy) * F_ROWB;
        ozv[i] = zt * 2 + zz;
        oyv[i] = yt * 8 + yy;
    }
    float bvv[4];
    #pragma unroll
    for (int v = 0; v < 4; ++v) {
        int co = 4 * g + v;
        bvv[v] = (co < 13) ? Bv[co] : 0.0f;
    }
    f32x4 acc[4][4];
    #pragma unroll
    for (int i = 0; i < 4; ++i)
        #pragma unroll
        for (int sh = 0; sh < 4; ++sh)
            acc[i][sh] = (f32x4){ bvv[0], bvv[1], bvv[2], bvv[3] };
    __syncthreads();

    #pragma unroll
    for (int s = 0; s < 13; ++s) {
        bf16x8 bb[4];
        #pragma unroll
        for (int i = 0; i < 4; ++i) {
            const char* p = (const char*)lds + (rowConst[s] + tileOff[i] + 8 * lx);
            uint2 lo = *(const uint2*)p;
            uint2 hi = *(const uint2*)(p + 8);
            union { unsigned u[4]; bf16x8 v; } tmp;
            tmp.u[0] = lo.x; tmp.u[1] = lo.y; tmp.u[2] = hi.x; tmp.u[3] = hi.y;
            bb[i] = tmp.v;
        }
        unsigned a0 = wf[s][0], a1 = wf[s][1], a2 = wf[s][2], a3 = wf[s][3];
        #pragma unroll
        for (int sh = 0; sh < 4; ++sh) {
            if (sh) {
                unsigned n1 = (a1 << 16) | (a0 >> 16);
                unsigned n2 = (a2 << 16) | (a1 >> 16);
                unsigned n3 = (a3 << 16) | (a2 >> 16);
                a0 <<= 16; a1 = n1; a2 = n2; a3 = n3;
            }
            union { unsigned u[4]; bf16x8 v; } av;
            av.u[0] = a0; av.u[1] = a1; av.u[2] = a2; av.u[3] = a3;
            #pragma unroll
            for (int i = 0; i < 4; ++i)
                acc[i][sh] = __builtin_amdgcn_mfma_f32_16x16x32_bf16(av.v, bb[i], acc[i][sh], 0, 0, 0);
        }
    }
    #pragma unroll
    for (int i = 0; i < 4; ++i) {
        float* dst = O + ((((size_t)b * 13) * 64 + ozv[i]) * 64 + oyv[i]) * 64 + 4 * lx;
        #pragma unroll
        for (int v = 0; v < 4; ++v) {
            int co = 4 * g + v;
            if (co < 13) {
                f32x4 o4 = { fminf(fmaxf(acc[i][0][v], 0.0f), 100.0f),
                             fminf(fmaxf(acc[i][1][v], 0.0f), 100.0f),
                             fminf(fmaxf(acc[i][2][v], 0.0f), 100.0f),
                             fminf(fmaxf(acc[i][3][v], 0.0f), 100.0f) };
                *(f32x4*)(dst + (size_t)co * 262144) = o4;
            }
        }
    }
}

extern "C" void kernel_launch(void* const* d_in, const int* in_sizes, int n_in,
                              void* d_out, int out_size, void* d_ws, size_t ws_size,
                              hipStream_t stream) {
    const float* X  = (const float*)d_in[0];
    const float* W  = (const float*)d_in[1];
    const float* Bv = (const float*)d_in[2];
    float* O = (float*)d_out;

    if (ws_size >= P_BYTES) {
        u16* P = (u16*)d_ws;
        pad_bf16<<<10404, 256, 0, stream>>>(X, P);               // 2,663,424 tasks
        conv13_async<<<dim3(8, 4, 16), 256, 0, stream>>>(P, W, Bv, O);
    } else {
        conv13_mfma_shift<<<dim3(8, 32, 16), 256, 0, stream>>>(X, W, Bv, O);
    }
}